// Round 6
// baseline (625.498 us; speedup 1.0000x reference)
//
#include <hip/hip_runtime.h>

// ---------- types ----------
typedef __attribute__((ext_vector_type(8))) short short8;   // 8 bf16 (4 VGPR)
typedef __attribute__((ext_vector_type(4))) short short4v;  // 4 bf16
typedef __attribute__((ext_vector_type(4))) float float4v;  // 4 fp32

__device__ __forceinline__ float bf2f(short s) {
  union { float f; unsigned u; } cv; cv.u = ((unsigned)(unsigned short)s) << 16; return cv.f;
}
__device__ __forceinline__ short f2bf(float f) {   // RNE fp32->bf16, inputs never NaN
  union { float f; unsigned u; } cv; cv.f = f;
  unsigned u = cv.u;
  unsigned r = u + 0x7FFFu + ((u >> 16) & 1u);
  return (short)(r >> 16);
}
__device__ __forceinline__ float gelu_f(float v) {
  return 0.5f * v * (1.0f + erff(v * 0.70710678118654752440f));
}
// async global->LDS, 16 B per lane; LDS dest = wave-uniform base + lane*16
__device__ __forceinline__ void glds16(const short* g, short* l) {
  __builtin_amdgcn_global_load_lds(
      (const __attribute__((address_space(1))) void*)g,
      (__attribute__((address_space(3))) void*)l, 16, 0, 0);
}
// XOR-swizzled LDS index for a [128][128] bf16 tile (16B segs swizzled by row)
__device__ __forceinline__ int swz(int r, int c) {
  return r * 128 + ((((c >> 3) ^ (r & 7)) << 3) | (c & 7));
}

// ---------- prep: x->bf16 (mask-skipped), weight conversions, seeds, zero-init ----------
__global__ void prep_wide(const float* __restrict__ x, const float* __restrict__ w1,
                          const float* __restrict__ w2,
                          const float* __restrict__ proj_w, const float* __restrict__ ffn_w1,
                          const float* __restrict__ ffn_w2, const float* __restrict__ out_w,
                          const float* __restrict__ A, const int* __restrict__ seq_lens,
                          short* __restrict__ xB,
                          short* __restrict__ w1T, short* __restrict__ w2T,
                          short* __restrict__ projB, short* __restrict__ ffn1B,
                          short* __restrict__ ffn2B, short* __restrict__ outB,
                          short* __restrict__ P1, short* __restrict__ P1t,
                          short* __restrict__ P2t,
                          float* __restrict__ hFtail, int* __restrict__ encCnt,
                          int* __restrict__ gcnt)
{
  int idx = blockIdx.x * 256 + threadIdx.x;
  if (idx < 3145728) {                       // x -> bf16 (float4 units), skip masked rows
    int row = idx / 96;                      // 384 floats = 96 float4 per row
    int t = row & 4095, b = row >> 12;
    if (t >= seq_lens[b]) return;            // xB stays poison there (never used)
    float4v v = ((const float4v*)x)[idx];
    short4v o;
#pragma unroll
    for (int j = 0; j < 4; j++) o[j] = f2bf(v[j]);
    ((short4v*)xB)[idx] = o;
    return;
  }
  idx -= 3145728;
  if (idx < 393216) {                        // w1T[n][k] = w1[k][n]
    int n = idx / 384, k = idx % 384;
    w1T[idx] = f2bf(w1[k * 1024 + n]);
    return;
  }
  idx -= 393216;
  if (idx < 131072) {                        // w2T[n][k] = w2[k][n]
    int n = idx / 1024, k = idx % 1024;
    w2T[idx] = f2bf(w2[k * 128 + n]);
    return;
  }
  idx -= 131072;
  if (idx < 131072) { projB[idx] = f2bf(proj_w[idx]); return; }
  idx -= 131072;
  if (idx < 524288) { ffn1B[idx] = f2bf(ffn_w1[idx]); return; }
  idx -= 524288;
  if (idx < 524288) { ffn2B[idx] = f2bf(ffn_w2[idx]); return; }
  idx -= 524288;
  if (idx < 1048576) { outB[idx] = f2bf(out_w[idx]); return; }
  idx -= 1048576;
  if (idx < 16384) {                         // identity (slot 63) + A (slot 62)
    int i = idx >> 7, j = idx & 127;
    short idv = f2bf((i == j) ? 1.0f : 0.0f);
    P1[i * 8192 + 63 * 128 + j] = idv;
    P1t[(63 * 128 + j) * 128 + i] = idv;
    P2t[(63 * 128 + j) * 128 + i] = idv;
    short ab = f2bf(A[idx]);
    P1[i * 8192 + 62 * 128 + j] = ab;
    P1t[(62 * 128 + j) * 128 + i] = ab;      // also serves as A^T operand for mega powers
    return;
  }
  idx -= 16384;
  if (idx < 2048) { hFtail[idx] = 0.f; return; }   // combine accumulators
  idx -= 2048;
  if (idx < 512) { encCnt[idx] = 0; return; }      // enc tile arrival counters
  idx -= 512;
  if (idx < 16) gcnt[idx] = 0;                     // mega grid-barrier counters
}

// ---------- fused encoder, 4-way nc-split + in-kernel reduction ----------
__global__ __launch_bounds__(256) void enc_fused(
    const short* __restrict__ xB, const short* __restrict__ w1T,
    const short* __restrict__ w2T, const float* __restrict__ b1,
    const float* __restrict__ b2, float* __restrict__ encP,
    short* __restrict__ seqs, int* __restrict__ encCnt,
    const int* __restrict__ seq_lens)
{
  int m0 = blockIdx.x * 64;
  { int b = m0 >> 12, t = m0 & 4095; if (t >= seq_lens[b]) return; }
  int nc0 = blockIdx.y * 2;

  __shared__ __align__(16) short As[64 * 64];     // x tile, 8 KB
  __shared__ __align__(16) short Ws[128 * 64];    // w1/w2 chunk, 16 KB
  __shared__ __align__(16) short midb[64 * 128];  // GELU-mid chunk, 16 KB
  __shared__ int lastf;

  int tid = threadIdx.x, lane = tid & 63, wave = tid >> 6;
  int l15 = lane & 15, quad = lane >> 4;
  int lr = lane >> 3, lseg = lane & 7;

  float4v accO[4][2];
#pragma unroll
  for (int i = 0; i < 4; i++)
#pragma unroll
    for (int j = 0; j < 2; j++) accO[i][j] = 0;

  for (int nci = 0; nci < 2; ++nci) {
    int nc = nc0 + nci;
    float4v accM[4][2];
#pragma unroll
    for (int i = 0; i < 4; i++)
#pragma unroll
      for (int j = 0; j < 2; j++) accM[i][j] = 0;

    // ---- GEMM1 chunk: mid[64][128] = x[64][384] @ w1T[nc*128..+128][384]^T ----
    for (int ks = 0; ks < 6; ++ks) {
      int kk = ks * 64;
#pragma unroll
      for (int i = 0; i < 2; i++) {                 // x: 64 rows
        int rowg = wave * 16 + i * 8;
        glds16(xB + (size_t)(m0 + rowg + lr) * 384 + kk + (lseg ^ lr) * 8, &As[rowg * 64]);
      }
#pragma unroll
      for (int i = 0; i < 4; i++) {                 // w1 chunk: 128 rows
        int rowg = wave * 32 + i * 8;
        glds16(w1T + (size_t)(nc * 128 + rowg + lr) * 384 + kk + (lseg ^ lr) * 8, &Ws[rowg * 64]);
      }
      __syncthreads();
#pragma unroll
      for (int kh = 0; kh < 2; kh++) {
        int s = kh * 4 + quad;
        short8 af[4], bfr[2];
#pragma unroll
        for (int im = 0; im < 4; im++) {
          int r = im * 16 + l15;
          af[im] = *(short8*)&As[r * 64 + ((s ^ (r & 7)) * 8)];
        }
#pragma unroll
        for (int in = 0; in < 2; in++) {
          int r = wave * 32 + in * 16 + l15;
          bfr[in] = *(short8*)&Ws[r * 64 + ((s ^ (r & 7)) * 8)];
        }
#pragma unroll
        for (int im = 0; im < 4; im++)
#pragma unroll
          for (int in = 0; in < 2; in++)
            accM[im][in] = __builtin_amdgcn_mfma_f32_16x16x32_bf16(af[im], bfr[in], accM[im][in], 0, 0, 0);
      }
      __syncthreads();
    }
    // ---- GELU epilogue -> midb (A-operand layout, swizzled) ----
#pragma unroll
    for (int im = 0; im < 4; im++)
#pragma unroll
      for (int in = 0; in < 2; in++) {
        int k = wave * 32 + in * 16 + l15;          // mid column
        float bias = b1[nc * 128 + k];
#pragma unroll
        for (int reg = 0; reg < 4; reg++) {
          int m = im * 16 + quad * 4 + reg;
          float v = gelu_f(accM[im][in][reg] + bias);
          int s = k >> 3;
          int sw = (s & 8) | ((s & 7) ^ (m & 7));
          midb[m * 128 + sw * 8 + (k & 7)] = f2bf(v);
        }
      }
    __syncthreads();
    // ---- GEMM2 chunk: accO += mid[64][128] @ w2T[0..128][nc*128..+128]^T ----
#pragma unroll
    for (int ks2 = 0; ks2 < 2; ++ks2) {
      int kk = nc * 128 + ks2 * 64;
#pragma unroll
      for (int i = 0; i < 4; i++) {                 // w2 chunk: 128 rows (out cols)
        int rowg = wave * 32 + i * 8;
        glds16(w2T + (size_t)(rowg + lr) * 1024 + kk + (lseg ^ lr) * 8, &Ws[rowg * 64]);
      }
      __syncthreads();
#pragma unroll
      for (int kh = 0; kh < 2; kh++) {
        short8 af[4], bfr[2];
#pragma unroll
        for (int im = 0; im < 4; im++) {
          int m = im * 16 + l15;
          int kb = ks2 * 64 + kh * 32 + quad * 8;
          int s = kb >> 3;
          int sw = (s & 8) | ((s & 7) ^ (m & 7));
          af[im] = *(short8*)&midb[m * 128 + sw * 8];
        }
#pragma unroll
        for (int in = 0; in < 2; in++) {
          int r = wave * 32 + in * 16 + l15;
          int s = kh * 4 + quad;
          bfr[in] = *(short8*)&Ws[r * 64 + ((s ^ (r & 7)) * 8)];
        }
#pragma unroll
        for (int im = 0; im < 4; im++)
#pragma unroll
          for (int in = 0; in < 2; in++)
            accO[im][in] = __builtin_amdgcn_mfma_f32_16x16x32_bf16(af[im], bfr[in], accO[im][in], 0, 0, 0);
      }
      __syncthreads();
    }
  }
  // ---- write fp32 partial slice ----
  float* outp = encP + ((size_t)blockIdx.y << 22);   // 32768*128 = 1<<22
#pragma unroll
  for (int im = 0; im < 4; im++)
#pragma unroll
    for (int in = 0; in < 2; in++) {
      int n = wave * 32 + in * 16 + l15;
#pragma unroll
      for (int reg = 0; reg < 4; reg++) {
        int m = m0 + im * 16 + quad * 4 + reg;
        outp[(size_t)m * 128 + n] = accO[im][in][reg];
      }
    }
  // ---- last-arriver reduces the 4 slabs + b2 -> bf16 seqs ----
  __threadfence();
  if (tid == 0) lastf = (atomicAdd(&encCnt[blockIdx.x], 1) == 3);
  __syncthreads();
  if (lastf) {
    __threadfence();
#pragma unroll
    for (int i = 0; i < 8; i++) {
      int f4 = tid + i * 256;
      int m = m0 + (f4 >> 5);
      int cg = f4 & 31;
      size_t off = (size_t)m * 128 + cg * 4;
      float4v v = *(const float4v*)&encP[off];
#pragma unroll
      for (int y = 1; y < 4; y++) {
        float4v w = *(const float4v*)&encP[((size_t)y << 22) + off];
#pragma unroll
        for (int q = 0; q < 4; q++) v[q] += w[q];
      }
      float4v bb = *(const float4v*)&b2[cg * 4];
      short4v o;
#pragma unroll
      for (int q = 0; q < 4; q++) o[q] = f2bf(v[q] + bb[q]);
      *(short4v*)&seqs[off] = o;
    }
  }
}

// ---------- megakernel: powers -> V-GEMM -> combine -> proj -> ffn1 -> ffn2 -> out ----------
// 128 blocks (all co-resident on 256 CUs); phases separated by device-scope spin barriers.
__device__ __forceinline__ void gsync(int* c, int n) {
  __threadfence();
  __syncthreads();
  if (threadIdx.x == 0) {
    atomicAdd(c, 1);
    while (atomicAdd(c, 0) < n) __builtin_amdgcn_s_sleep(8);
  }
  __syncthreads();
  __threadfence();
}

__global__ __launch_bounds__(256) void mega(
    const float* __restrict__ A, const int* __restrict__ seq_lens,
    short* __restrict__ P1, short* __restrict__ P1t, short* __restrict__ P2t,
    const short* __restrict__ seqs, float* __restrict__ Vz, float* __restrict__ hFtail,
    const short* __restrict__ projB, const float* __restrict__ proj_b,
    float* __restrict__ projected,
    const float* __restrict__ g1, const float* __restrict__ b1ln,
    const short* __restrict__ ffn1B, float* __restrict__ ffn1raw,
    const float* __restrict__ fb1, const short* __restrict__ ffn2B,
    float* __restrict__ ffn2raw, const float* __restrict__ fb2,
    const float* __restrict__ g2, const float* __restrict__ b2ln,
    const short* __restrict__ outB, const float* __restrict__ out_b,
    float* __restrict__ d_out, int* __restrict__ gcnt)
{
  __shared__ __align__(16) char smem[65536];
  int bid = blockIdx.x, t = threadIdx.x;
  int lane = t & 63, wave = t >> 6, l15 = lane & 15, quad = lane >> 4;

  // ===== phase 0: power tables (blocks 0..125, independent binary exponentiation) =====
  if (bid < 126) {
    short* cur  = (short*)smem;          // 32 KB, swizzled [128][128]
    short* curT = cur + 16384;           // 32 KB, swizzled transpose
    const short* ATg = P1t + (size_t)62 * 16384;   // A^T bf16 (from prep), [n*128+k]
    for (int i = t; i < 16384; i += 256) {
      int r = i >> 7, c = i & 127;
      short v = f2bf(A[i]);
      cur[swz(r, c)] = v;
      curT[swz(c, r)] = v;
    }
    __syncthreads();
    int table1 = bid < 63;
    int e = table1 ? bid + 1 : bid - 62;
    int E = table1 ? e : (e << 6);       // table2: (A^64)^e = A^(64e)
    int mk = 31 - __clz(E);
    auto mmstep = [&](const short* YT, bool gB) {   // cur = cur * Y (Y given as Y^T)
      short8 af[2][4], bfv[8][4];
#pragma unroll
      for (int mt = 0; mt < 2; mt++)
#pragma unroll
        for (int ks = 0; ks < 4; ks++) {
          int r = wave * 32 + mt * 16 + l15, s = ks * 4 + quad;
          af[mt][ks] = *(const short8*)&cur[r * 128 + ((s ^ (r & 7)) << 3)];
        }
#pragma unroll
      for (int nt = 0; nt < 8; nt++)
#pragma unroll
        for (int ks = 0; ks < 4; ks++) {
          int n = nt * 16 + l15;
          if (gB) bfv[nt][ks] = *(const short8*)&YT[n * 128 + ks * 32 + quad * 8];
          else {
            int s = ks * 4 + quad;
            bfv[nt][ks] = *(const short8*)&YT[n * 128 + ((s ^ (n & 7)) << 3)];
          }
        }
      __syncthreads();                   // all frags read before in-place overwrite
      float4v acc[2][8];
#pragma unroll
      for (int mt = 0; mt < 2; mt++)
#pragma unroll
        for (int nt = 0; nt < 8; nt++) acc[mt][nt] = 0;
#pragma unroll
      for (int ks = 0; ks < 4; ks++)
#pragma unroll
        for (int mt = 0; mt < 2; mt++)
#pragma unroll
          for (int nt = 0; nt < 8; nt++)
            acc[mt][nt] = __builtin_amdgcn_mfma_f32_16x16x32_bf16(af[mt][ks], bfv[nt][ks], acc[mt][nt], 0, 0, 0);
#pragma unroll
      for (int mt = 0; mt < 2; mt++)
#pragma unroll
        for (int nt = 0; nt < 8; nt++)
#pragma unroll
          for (int reg = 0; reg < 4; reg++) {
            int m = wave * 32 + mt * 16 + quad * 4 + reg;
            int n = nt * 16 + l15;
            short v = f2bf(acc[mt][nt][reg]);
            cur[swz(m, n)] = v;
            curT[swz(n, m)] = v;
          }
      __syncthreads();
    };
    for (int k = mk - 1; k >= 0; --k) {
      mmstep(curT, false);               // cur = cur^2
      if ((E >> k) & 1) mmstep(ATg, true);   // cur = cur * A
    }
    int slot = 63 - e;
    if (!(table1 && e == 1)) {           // e==1 table1 already written by prep
      for (int i = t; i < 16384; i += 256) {
        int r = i >> 7, c = i & 127;
        short v = cur[swz(r, c)];
        if (table1) {
          P1[r * 8192 + slot * 128 + c] = v;
          P1t[(slot * 128 + c) * 128 + r] = v;
        } else {
          P2t[(slot * 128 + c) * 128 + r] = v;
        }
      }
    }
  }
  gsync(&gcnt[0], 128);

  // ===== phase 1: V-GEMM (all 128 blocks): Vz[z] = seqs-view @ P1^T over k-chunk z =====
  {
    short* As = (short*)smem;            // 16 KB
    short* Bs = As + 8192;               // 16 KB
    int z = bid & 31, mt0 = bid >> 5;
    int m0 = mt0 * 128, kBase = z * 256;
    int wm = wave & 1, wn = wave >> 1, lr = lane >> 3, lseg = lane & 7;
    float4v acc[4][4];
#pragma unroll
    for (int i = 0; i < 4; i++)
#pragma unroll
      for (int j = 0; j < 4; j++) acc[i][j] = 0;
    for (int ks = 0; ks < 4; ++ks) {
      int kk = kBase + ks * 64;
#pragma unroll
      for (int i = 0; i < 4; i++) {
        int rowg = wave * 32 + i * 8;
        glds16(seqs + (size_t)(m0 + rowg + lr) * 8192 + kk + (lseg ^ lr) * 8, &As[rowg * 64]);
        glds16(P1 + (size_t)(rowg + lr) * 8192 + kk + (lseg ^ lr) * 8, &Bs[rowg * 64]);
      }
      __syncthreads();
#pragma unroll
      for (int kh = 0; kh < 2; kh++) {
        int s = kh * 4 + quad;
        short8 af[4], bfr[4];
#pragma unroll
        for (int im = 0; im < 4; im++) {
          int r = wm * 64 + im * 16 + l15;
          af[im] = *(short8*)&As[r * 64 + ((s ^ (r & 7)) * 8)];
        }
#pragma unroll
        for (int in = 0; in < 4; in++) {
          int r = wn * 64 + in * 16 + l15;
          bfr[in] = *(short8*)&Bs[r * 64 + ((s ^ (r & 7)) * 8)];
        }
#pragma unroll
        for (int im = 0; im < 4; im++)
#pragma unroll
          for (int in = 0; in < 4; in++)
            acc[im][in] = __builtin_amdgcn_mfma_f32_16x16x32_bf16(af[im], bfr[in], acc[im][in], 0, 0, 0);
      }
      __syncthreads();
    }
    float* outz = Vz + (size_t)z * 65536;
#pragma unroll
    for (int im = 0; im < 4; im++)
#pragma unroll
      for (int in = 0; in < 4; in++) {
        int n = wn * 64 + in * 16 + l15;
#pragma unroll
        for (int reg = 0; reg < 4; reg++) {
          int m = m0 + wm * 64 + im * 16 + quad * 4 + reg;
          outz[(size_t)m * 128 + n] = acc[im][in][reg];
        }
      }
  }
  gsync(&gcnt[1], 128);

  // ===== phase 2: combine (blocks 0..63): hF via P2 / tail via P1, atomics into hFtail =====
  if (bid < 64) {
    short* X = (short*)smem;             // [256][8] bf16
    int pp = bid >> 5, ks = bid & 31;
    for (int e = t; e < 2048; e += 256) {
      int klocal = e >> 3, b = e & 7;
      int cp = ks * 2 + (klocal >> 7), i = klocal & 127;
      int L = seq_lens[b];
      if (pp == 0) {
        int F = L >> 6, sh = 64 - F;
        float v = 0.f;
        if (cp >= sh) {
          int row = (b * 64 + (cp - sh)) * 128 + i;
#pragma unroll
          for (int z = 0; z < 32; z++) v += Vz[(size_t)z * 65536 + row];
        }
        X[e] = f2bf(v);
      } else {
        int F = L >> 6, rr = L & 63, sh = 64 - rr;
        short s = 0;
        if (cp >= sh) s = seqs[((size_t)b * 4096 + F * 64 + (cp - sh)) * 128 + i];
        X[e] = s;
      }
    }
    __syncthreads();
    const short* P = pp ? P1t : P2t;
    float* outp = hFtail + pp * 1024;
    int i = t & 127, g = t >> 7;
    float acc[4] = {0, 0, 0, 0};
    for (int kl = 0; kl < 256; ++kl) {
      int k = ks * 256 + kl;
      float pv = bf2f(P[k * 128 + i]);
      short4v xv = *(const short4v*)(X + kl * 8 + g * 4);
#pragma unroll
      for (int q = 0; q < 4; q++) acc[q] += bf2f(xv[q]) * pv;
    }
#pragma unroll
    for (int q = 0; q < 4; q++) atomicAdd(&outp[(g * 4 + q) * 128 + i], acc[q]);
  }
  gsync(&gcnt[2], 128);

  // ===== phase 3: proj (blocks 0..15): h = A^rr hF + tail, proj matvec =====
  if (bid < 16) {
    short* hT = (short*)smem;                      // [128][8] bf16
    float (*red)[64][8] = (float(*)[64][8])(smem + 4096);
    {
      int b = t >> 5, i4 = (t & 31) * 4;
      int rr = seq_lens[b] & 63;
      const short* M = P1t + (size_t)(63 - rr) * 16384;   // (A^rr)[i][j] = M[j*128+i]
      const float* hF = hFtail + b * 128;
      float acc[4];
#pragma unroll
      for (int q = 0; q < 4; q++) acc[q] = hFtail[1024 + b * 128 + i4 + q];
      for (int j = 0; j < 128; ++j) {
        float hv = hF[j];
        short4v mv = *(const short4v*)&M[j * 128 + i4];
#pragma unroll
        for (int q = 0; q < 4; q++) acc[q] += bf2f(mv[q]) * hv;
      }
#pragma unroll
      for (int q = 0; q < 4; q++) hT[(i4 + q) * 8 + b] = f2bf(acc[q]);
    }
    __syncthreads();
    int c = t & 63, sl = t >> 6;
    int n = bid * 64 + c;
    float acc[8] = {0, 0, 0, 0, 0, 0, 0, 0};
    for (int k = sl * 32; k < sl * 32 + 32; ++k) {
      short8 xv = *(short8*)&hT[k * 8];
      float wv = bf2f(projB[k * 1024 + n]);
#pragma unroll
      for (int b = 0; b < 8; b++) acc[b] += bf2f(xv[b]) * wv;
    }
#pragma unroll
    for (int b = 0; b < 8; b++) red[sl][c][b] = acc[b];
    __syncthreads();
    if (sl == 0) {
#pragma unroll
      for (int s = 1; s < 4; s++)
#pragma unroll
        for (int b = 0; b < 8; b++) acc[b] += red[s][c][b];
      float bn = proj_b[n];
#pragma unroll
      for (int b = 0; b < 8; b++) projected[b * 1024 + n] = acc[b] + bn;
    }
  }
  gsync(&gcnt[3], 128);

  // ===== phase 4: ffn1 (blocks 0..7): LN1(projected) @ ffn_w1 -> ffn1raw (full K) =====
  if (bid < 8) {
    float (*part)[32][2] = (float(*)[32][2])smem;
    float (*stats)[2] = (float(*)[2])(smem + 2048);
    short* xT = (short*)(smem + 4096);             // [1024][8] bf16, 16 KB
    float (*red)[64][8] = (float(*)[64][8])(smem + 4096 + 16384);
    { int b = t >> 5, j0 = t & 31; float s = 0, q = 0;
      for (int k = j0 * 32; k < j0 * 32 + 32; ++k) { float v = projected[b * 1024 + k]; s += v; q += v * v; }
      part[b][j0][0] = s; part[b][j0][1] = q; }
    __syncthreads();
    if (t < 8) {
      float s = 0, q = 0;
      for (int j = 0; j < 32; j++) { s += part[t][j][0]; q += part[t][j][1]; }
      float mu = s * (1.0f / 1024.0f);
      float var = q * (1.0f / 1024.0f) - mu * mu;
      stats[t][0] = mu; stats[t][1] = rsqrtf(var + 1e-5f);
    }
    __syncthreads();
    for (int idx = t; idx < 8192; idx += 256) {
      int k = idx >> 3, b = idx & 7;
      float v = (projected[b * 1024 + k] - stats[b][0]) * stats[b][1] * g1[k] + b1ln[k];
      xT[k * 8 + b] = f2bf(v);
    }
    __syncthreads();
    int c = t & 63, sl = t >> 6;
    int n = bid * 64 + c;
    float acc[8] = {0, 0, 0, 0, 0, 0, 0, 0};
    for (int k = sl * 256; k < sl * 256 + 256; ++k) {
      short8 xv = *(short8*)&xT[k * 8];
      float wv = bf2f(ffn1B[(size_t)k * 512 + n]);
#pragma unroll
      for (int b = 0; b < 8; b++) acc[b] += bf2f(xv[b]) * wv;
    }
#pragma unroll
    for (int b = 0; b < 8; b++) red[sl][c][b] = acc[b];
    __syncthreads();
    if (sl == 0) {
#pragma unroll
      for (int s = 1; s < 4; s++)
#pragma unroll
        for (int b = 0; b < 8; b++) acc[b] += red[s][c][b];
#pragma unroll
      for (int b = 0; b < 8; b++) ffn1raw[b * 512 + n] = acc[b];
    }
  }
  gsync(&gcnt[4], 128);

  // ===== phase 5: ffn2 (blocks 0..15): gelu(ffn1raw+b1) @ ffn_w2 -> ffn2raw (full K) =====
  if (bid < 16) {
    short* xT = (short*)smem;                      // [512][8] bf16, 8 KB
    float (*red)[64][8] = (float(*)[64][8])(smem + 8192);
    for (int idx = t; idx < 4096; idx += 256) {
      int k = idx >> 3, b = idx & 7;
      float v = gelu_f(ffn1raw[b * 512 + k] + fb1[k]);
      xT[k * 8 + b] = f2bf(v);
    }
    __syncthreads();
    int c = t & 63, sl = t >> 6;
    int n = bid * 64 + c;
    float acc[8] = {0, 0, 0, 0, 0, 0, 0, 0};
    for (int k = sl * 128; k < sl * 128 + 128; ++k) {
      short8 xv = *(short8*)&xT[k * 8];
      float wv = bf2f(ffn2B[(size_t)k * 1024 + n]);
#pragma unroll
      for (int b = 0; b < 8; b++) acc[b] += bf2f(xv[b]) * wv;
    }
#pragma unroll
    for (int b = 0; b < 8; b++) red[sl][c][b] = acc[b];
    __syncthreads();
    if (sl == 0) {
#pragma unroll
      for (int s = 1; s < 4; s++)
#pragma unroll
        for (int b = 0; b < 8; b++) acc[b] += red[s][c][b];
#pragma unroll
      for (int b = 0; b < 8; b++) ffn2raw[b * 1024 + n] = acc[b];
    }
  }
  gsync(&gcnt[5], 128);

  // ===== phase 6: out (blocks 0..15): LN2(ffn2raw+b2+projected) @ out_w + out_b -> d_out =====
  if (bid < 16) {
    float (*part)[32][2] = (float(*)[32][2])smem;
    float (*stats)[2] = (float(*)[2])(smem + 2048);
    short* xT = (short*)(smem + 4096);             // [1024][8] bf16, 16 KB
    float (*red)[64][8] = (float(*)[64][8])(smem + 4096 + 16384);
    { int b = t >> 5, j0 = t & 31; float s = 0, q = 0;
      for (int k = j0 * 32; k < j0 * 32 + 32; ++k) {
        float v = ffn2raw[b * 1024 + k] + fb2[k] + projected[b * 1024 + k];
        s += v; q += v * v;
      }
      part[b][j0][0] = s; part[b][j0][1] = q; }
    __syncthreads();
    if (t < 8) {
      float s = 0, q = 0;
      for (int j = 0; j < 32; j++) { s += part[t][j][0]; q += part[t][j][1]; }
      float mu = s * (1.0f / 1024.0f);
      float var = q * (1.0f / 1024.0f) - mu * mu;
      stats[t][0] = mu; stats[t][1] = rsqrtf(var + 1e-5f);
    }
    __syncthreads();
    for (int idx = t; idx < 8192; idx += 256) {
      int k = idx >> 3, b = idx & 7;
      float v = ffn2raw[b * 1024 + k] + fb2[k] + projected[b * 1024 + k];
      v = (v - stats[b][0]) * stats[b][1] * g2[k] + b2ln[k];
      xT[k * 8 + b] = f2bf(v);
    }
    __syncthreads();
    int c = t & 63, sl = t >> 6;
    int n = bid * 64 + c;
    float acc[8] = {0, 0, 0, 0, 0, 0, 0, 0};
    for (int k = sl * 256; k < sl * 256 + 256; ++k) {
      short8 xv = *(short8*)&xT[k * 8];
      float wv = bf2f(outB[(size_t)k * 1024 + n]);
#pragma unroll
      for (int b = 0; b < 8; b++) acc[b] += bf2f(xv[b]) * wv;
    }
#pragma unroll
    for (int b = 0; b < 8; b++) red[sl][c][b] = acc[b];
    __syncthreads();
    if (sl == 0) {
#pragma unroll
      for (int s = 1; s < 4; s++)
#pragma unroll
        for (int b = 0; b < 8; b++) acc[b] += red[s][c][b];
      float bn = out_b[n];
#pragma unroll
      for (int b = 0; b < 8; b++) d_out[b * 1024 + n] = acc[b] + bn;
    }
  }
}

// ---------- host ----------
extern "C" void kernel_launch(void* const* d_in, const int* in_sizes, int n_in,
                              void* d_out, int out_size, void* d_ws, size_t ws_size,
                              hipStream_t stream)
{
  (void)in_sizes; (void)n_in; (void)out_size; (void)ws_size;
  const float* x      = (const float*)d_in[0];
  const int* seq_lens = (const int*)d_in[1];
  const float* A      = (const float*)d_in[2];
  const float* enc_w1 = (const float*)d_in[3];
  const float* enc_b1 = (const float*)d_in[4];
  const float* enc_w2 = (const float*)d_in[5];
  const float* enc_b2 = (const float*)d_in[6];
  const float* proj_w = (const float*)d_in[7];
  const float* proj_b = (const float*)d_in[8];
  const float* ln1_g  = (const float*)d_in[9];
  const float* ln1_b  = (const float*)d_in[10];
  const float* ffn_w1 = (const float*)d_in[11];
  const float* ffn_b1 = (const float*)d_in[12];
  const float* ffn_w2 = (const float*)d_in[13];
  const float* ffn_b2 = (const float*)d_in[14];
  const float* ln2_g  = (const float*)d_in[15];
  const float* ln2_b  = (const float*)d_in[16];
  const float* out_w  = (const float*)d_in[17];
  const float* out_b  = (const float*)d_in[18];

  char* p = (char*)d_ws;
  auto alloc = [&](size_t bytes) { char* r = p; p += (bytes + 255) & ~(size_t)255; return r; };
  short* xB    = (short*)alloc(32768ull * 384 * 2);     // 25 MB
  float* encP  = (float*)alloc(4ull * 32768 * 128 * 4); // 64 MB partials
  short* seqs  = (short*)alloc(32768ull * 128 * 2);     // 8.4 MB
  short* w1T   = (short*)alloc(1024ull * 384 * 2);
  short* w2T   = (short*)alloc(128ull * 1024 * 2);
  short* projB = (short*)alloc(128ull * 1024 * 2);
  short* ffn1B = (short*)alloc(1024ull * 512 * 2);
  short* ffn2B = (short*)alloc(512ull * 1024 * 2);
  short* outB  = (short*)alloc(1024ull * 1024 * 2);
  short* P1    = (short*)alloc(128ull * 8192 * 2);      // [i][(63-e)*128+j] = A^e
  short* P1t   = (short*)alloc(8192ull * 128 * 2);
  short* P2t   = (short*)alloc(8192ull * 128 * 2);
  float* Vz    = (float*)alloc(32ull * 512 * 128 * 4);  // per-z V partials
  float* hFtail  = (float*)alloc(2048ull * 4);          // zeroed by prep
  float* projected = (float*)alloc(8ull * 1024 * 4);
  float* ffn1raw = (float*)alloc(8ull * 512 * 4);
  float* ffn2raw = (float*)alloc(8ull * 1024 * 4);
  int*   encCnt  = (int*)alloc(512ull * 4);             // zeroed by prep
  int*   gcnt    = (int*)alloc(16ull * 4);              // zeroed by prep

  // node 1: all conversions + seeds + zero-init (replaces memsets)
  prep_wide<<<23115, 256, 0, stream>>>(x, enc_w1, enc_w2, proj_w, ffn_w1, ffn_w2, out_w,
      A, seq_lens, xB, w1T, w2T, projB, ffn1B, ffn2B, outB, P1, P1t, P2t,
      hFtail, encCnt, gcnt);

  // node 2: fused encoder (GEMM1+GELU+GEMM2, 4-way split) + in-kernel reduction -> seqs
  enc_fused<<<dim3(512, 4), 256, 0, stream>>>(xB, w1T, w2T, enc_b1, enc_b2,
      encP, seqs, encCnt, seq_lens);

  // node 3: powers + recurrence + decoder megakernel (spin-barrier phases)
  mega<<<128, 256, 0, stream>>>(A, seq_lens, P1, P1t, P2t, seqs, Vz, hFtail,
      projB, proj_b, projected, ln1_g, ln1_b, ffn1B, ffn1raw, ffn_b1,
      ffn2B, ffn2raw, ffn_b2, ln2_g, ln2_b, outB, out_b, (float*)d_out, gcnt);
}

// Round 7
// 493.397 us; speedup vs baseline: 1.2677x; 1.2677x over previous
//
#include <hip/hip_runtime.h>

// ---------- types ----------
typedef __attribute__((ext_vector_type(8))) short short8;   // 8 bf16 (4 VGPR)
typedef __attribute__((ext_vector_type(4))) short short4v;  // 4 bf16
typedef __attribute__((ext_vector_type(4))) float float4v;  // 4 fp32

__device__ __forceinline__ float bf2f(short s) {
  union { float f; unsigned u; } cv; cv.u = ((unsigned)(unsigned short)s) << 16; return cv.f;
}
__device__ __forceinline__ short f2bf(float f) {   // RNE fp32->bf16, inputs never NaN
  union { float f; unsigned u; } cv; cv.f = f;
  unsigned u = cv.u;
  unsigned r = u + 0x7FFFu + ((u >> 16) & 1u);
  return (short)(r >> 16);
}
__device__ __forceinline__ float gelu_f(float v) {
  return 0.5f * v * (1.0f + erff(v * 0.70710678118654752440f));
}
// async global->LDS, 16 B per lane; LDS dest = wave-uniform base + lane*16
__device__ __forceinline__ void glds16(const short* g, short* l) {
  __builtin_amdgcn_global_load_lds(
      (const __attribute__((address_space(1))) void*)g,
      (__attribute__((address_space(3))) void*)l, 16, 0, 0);
}

// ---------- prep: x->bf16 (mask-skipped), weight conversions, seeds, zero-init ----------
__global__ void prep_wide(const float* __restrict__ x, const float* __restrict__ w1,
                          const float* __restrict__ w2,
                          const float* __restrict__ proj_w, const float* __restrict__ ffn_w1,
                          const float* __restrict__ ffn_w2, const float* __restrict__ out_w,
                          const float* __restrict__ A, const int* __restrict__ seq_lens,
                          short* __restrict__ xB,
                          short* __restrict__ w1T, short* __restrict__ w2T,
                          short* __restrict__ projB, short* __restrict__ ffn1B,
                          short* __restrict__ ffn2B, short* __restrict__ outB,
                          short* __restrict__ P1, short* __restrict__ P1t,
                          short* __restrict__ P2t,
                          short* __restrict__ Spow, short* __restrict__ SpowT,
                          float* __restrict__ hFtail, float* __restrict__ ffn1raw,
                          float* __restrict__ ffn2raw, float* __restrict__ dout0,
                          int* __restrict__ encCnt)
{
  int idx = blockIdx.x * 256 + threadIdx.x;
  if (idx < 3145728) {                       // x -> bf16 (float4 units), skip masked rows
    int row = idx / 96;                      // 384 floats = 96 float4 per row
    int t = row & 4095, b = row >> 12;
    if (t >= seq_lens[b]) return;            // xB stays poison there (never used)
    float4v v = ((const float4v*)x)[idx];
    short4v o;
#pragma unroll
    for (int j = 0; j < 4; j++) o[j] = f2bf(v[j]);
    ((short4v*)xB)[idx] = o;
    return;
  }
  idx -= 3145728;
  if (idx < 393216) {                        // w1T[n][k] = w1[k][n]
    int n = idx / 384, k = idx % 384;
    w1T[idx] = f2bf(w1[k * 1024 + n]);
    return;
  }
  idx -= 393216;
  if (idx < 131072) {                        // w2T[n][k] = w2[k][n]
    int n = idx / 1024, k = idx % 1024;
    w2T[idx] = f2bf(w2[k * 128 + n]);
    return;
  }
  idx -= 131072;
  if (idx < 131072) { projB[idx] = f2bf(proj_w[idx]); return; }
  idx -= 131072;
  if (idx < 524288) { ffn1B[idx] = f2bf(ffn_w1[idx]); return; }
  idx -= 524288;
  if (idx < 524288) { ffn2B[idx] = f2bf(ffn_w2[idx]); return; }
  idx -= 524288;
  if (idx < 1048576) { outB[idx] = f2bf(out_w[idx]); return; }
  idx -= 1048576;
  if (idx < 16384) {                         // identity slots (e=0) + A seed
    int i = idx >> 7, j = idx & 127;
    short idv = f2bf((i == j) ? 1.0f : 0.0f);
    P1[i * 8192 + 63 * 128 + j] = idv;
    P1t[(63 * 128 + j) * 128 + i] = idv;
    P2t[(63 * 128 + j) * 128 + i] = idv;
    short ab = f2bf(A[idx]);
    Spow[idx] = ab;                          // A^1 row-major
    SpowT[(size_t)j * 128 + i] = ab;         // transposed
    return;
  }
  idx -= 16384;
  if (idx < 2048) { hFtail[idx] = 0.f; return; }   // combine accumulators
  idx -= 2048;
  if (idx < 4096) { ffn1raw[idx] = 0.f; return; }
  idx -= 4096;
  if (idx < 8192) { ffn2raw[idx] = 0.f; return; }
  idx -= 8192;
  if (idx < 8192) { dout0[idx] = 0.f; return; }
  idx -= 8192;
  if (idx < 512) encCnt[idx] = 0;                  // enc tile arrival counters
}

// ---------- fused encoder, 4-way nc-split + in-kernel reduction ----------
// LDS: Ws (16 KB) + Mb (16 KB). x-tile As aliases Mb's low 8 KB (never live together).
__global__ __launch_bounds__(256) void enc_fused(
    const short* __restrict__ xB, const short* __restrict__ w1T,
    const short* __restrict__ w2T, const float* __restrict__ b1,
    const float* __restrict__ b2, float* __restrict__ encP,
    short* __restrict__ seqs, int* __restrict__ encCnt,
    const int* __restrict__ seq_lens)
{
  int m0 = blockIdx.x * 64;
  { int b = m0 >> 12, t = m0 & 4095; if (t >= seq_lens[b]) return; }
  int nc0 = blockIdx.y * 2;

  __shared__ __align__(16) short Ws[128 * 64];    // w1/w2 chunk, 16 KB
  __shared__ __align__(16) short Mb[64 * 128];    // GELU-mid chunk, 16 KB
  short* As = Mb;                                 // x tile aliases low 8 KB
  __shared__ int lastf;

  int tid = threadIdx.x, lane = tid & 63, wave = tid >> 6;
  int l15 = lane & 15, quad = lane >> 4;
  int lr = lane >> 3, lseg = lane & 7;

  float4v accO[4][2];
#pragma unroll
  for (int i = 0; i < 4; i++)
#pragma unroll
    for (int j = 0; j < 2; j++) accO[i][j] = 0;

  for (int nci = 0; nci < 2; ++nci) {
    int nc = nc0 + nci;
    float4v accM[4][2];
#pragma unroll
    for (int i = 0; i < 4; i++)
#pragma unroll
      for (int j = 0; j < 2; j++) accM[i][j] = 0;

    // ---- GEMM1 chunk: mid[64][128] = x[64][384] @ w1T[nc*128..+128][384]^T ----
    for (int ks = 0; ks < 6; ++ks) {
      int kk = ks * 64;
#pragma unroll
      for (int i = 0; i < 2; i++) {                 // x: 64 rows
        int rowg = wave * 16 + i * 8;
        glds16(xB + (size_t)(m0 + rowg + lr) * 384 + kk + (lseg ^ lr) * 8, &As[rowg * 64]);
      }
#pragma unroll
      for (int i = 0; i < 4; i++) {                 // w1 chunk: 128 rows
        int rowg = wave * 32 + i * 8;
        glds16(w1T + (size_t)(nc * 128 + rowg + lr) * 384 + kk + (lseg ^ lr) * 8, &Ws[rowg * 64]);
      }
      __syncthreads();
#pragma unroll
      for (int kh = 0; kh < 2; kh++) {
        int s = kh * 4 + quad;
        short8 af[4], bfr[2];
#pragma unroll
        for (int im = 0; im < 4; im++) {
          int r = im * 16 + l15;
          af[im] = *(short8*)&As[r * 64 + ((s ^ (r & 7)) * 8)];
        }
#pragma unroll
        for (int in = 0; in < 2; in++) {
          int r = wave * 32 + in * 16 + l15;
          bfr[in] = *(short8*)&Ws[r * 64 + ((s ^ (r & 7)) * 8)];
        }
#pragma unroll
        for (int im = 0; im < 4; im++)
#pragma unroll
          for (int in = 0; in < 2; in++)
            accM[im][in] = __builtin_amdgcn_mfma_f32_16x16x32_bf16(af[im], bfr[in], accM[im][in], 0, 0, 0);
      }
      __syncthreads();
    }
    // ---- GELU epilogue -> Mb (A-operand layout, swizzled); overwrites As region ----
#pragma unroll
    for (int im = 0; im < 4; im++)
#pragma unroll
      for (int in = 0; in < 2; in++) {
        int k = wave * 32 + in * 16 + l15;          // mid column
        float bias = b1[nc * 128 + k];
#pragma unroll
        for (int reg = 0; reg < 4; reg++) {
          int m = im * 16 + quad * 4 + reg;
          float v = gelu_f(accM[im][in][reg] + bias);
          int s = k >> 3;
          int sw = (s & 8) | ((s & 7) ^ (m & 7));
          Mb[m * 128 + sw * 8 + (k & 7)] = f2bf(v);
        }
      }
    __syncthreads();
    // ---- GEMM2 chunk: accO += mid[64][128] @ w2T[0..128][nc*128..+128]^T ----
#pragma unroll
    for (int ks2 = 0; ks2 < 2; ++ks2) {
      int kk = nc * 128 + ks2 * 64;
#pragma unroll
      for (int i = 0; i < 4; i++) {                 // w2 chunk: 128 rows (out cols)
        int rowg = wave * 32 + i * 8;
        glds16(w2T + (size_t)(rowg + lr) * 1024 + kk + (lseg ^ lr) * 8, &Ws[rowg * 64]);
      }
      __syncthreads();
#pragma unroll
      for (int kh = 0; kh < 2; kh++) {
        short8 af[4], bfr[2];
#pragma unroll
        for (int im = 0; im < 4; im++) {
          int m = im * 16 + l15;
          int kb = ks2 * 64 + kh * 32 + quad * 8;
          int s = kb >> 3;
          int sw = (s & 8) | ((s & 7) ^ (m & 7));
          af[im] = *(short8*)&Mb[m * 128 + sw * 8];
        }
#pragma unroll
        for (int in = 0; in < 2; in++) {
          int r = wave * 32 + in * 16 + l15;
          int s = kh * 4 + quad;
          bfr[in] = *(short8*)&Ws[r * 64 + ((s ^ (r & 7)) * 8)];
        }
#pragma unroll
        for (int im = 0; im < 4; im++)
#pragma unroll
          for (int in = 0; in < 2; in++)
            accO[im][in] = __builtin_amdgcn_mfma_f32_16x16x32_bf16(af[im], bfr[in], accO[im][in], 0, 0, 0);
      }
      __syncthreads();
    }
  }
  // ---- write fp32 partial slice ----
  float* outp = encP + ((size_t)blockIdx.y << 22);   // 32768*128 = 1<<22
#pragma unroll
  for (int im = 0; im < 4; im++)
#pragma unroll
    for (int in = 0; in < 2; in++) {
      int n = wave * 32 + in * 16 + l15;
#pragma unroll
      for (int reg = 0; reg < 4; reg++) {
        int m = m0 + im * 16 + quad * 4 + reg;
        outp[(size_t)m * 128 + n] = accO[im][in][reg];
      }
    }
  // ---- last-arriver reduces the 4 slabs + b2 -> bf16 seqs ----
  __threadfence();
  if (tid == 0) lastf = (atomicAdd(&encCnt[blockIdx.x], 1) == 3);
  __syncthreads();
  if (lastf) {
    __threadfence();
#pragma unroll
    for (int i = 0; i < 8; i++) {
      int f4 = tid + i * 256;
      int m = m0 + (f4 >> 5);
      int cg = f4 & 31;
      size_t off = (size_t)m * 128 + cg * 4;
      float4v v = *(const float4v*)&encP[off];
#pragma unroll
      for (int y = 1; y < 4; y++) {
        float4v w = *(const float4v*)&encP[((size_t)y << 22) + off];
#pragma unroll
        for (int q = 0; q < 4; q++) v[q] += w[q];
      }
      float4v bb = *(const float4v*)&b2[cg * 4];
      short4v o;
#pragma unroll
      for (int q = 0; q < 4; q++) o[q] = f2bf(v[q] + bb[q]);
      *(short4v*)&seqs[off] = o;
    }
  }
}

// ---------- single-block MFMA squaring chain ----------
// Spow[k]: k=0..6 -> A^(2^k); k=7..11 -> (A^64)^(2^(k-6)).
__global__ __launch_bounds__(256) void pow_chain(short* __restrict__ Spow,
                                                 short* __restrict__ SpowT)
{
  __shared__ short X[16384];    // cur, row-major
  __shared__ short XT[16384];   // cur, transposed
  int t = threadIdx.x;
  for (int i = t * 8; i < 16384; i += 2048) {
    *(short8*)&X[i]  = *(const short8*)&Spow[i];
    *(short8*)&XT[i] = *(const short8*)&SpowT[i];
  }
  __syncthreads();
  int lane = t & 63, wave = t >> 6, l15 = lane & 15, quad = lane >> 4;
  for (int step = 1; step <= 11; ++step) {
    short8 af[2][4], bfr[8][4];
#pragma unroll
    for (int mt = 0; mt < 2; mt++)
#pragma unroll
      for (int ks = 0; ks < 4; ks++)
        af[mt][ks] = *(short8*)&X[(wave * 32 + mt * 16 + l15) * 128 + ks * 32 + quad * 8];
#pragma unroll
    for (int nt = 0; nt < 8; nt++)
#pragma unroll
      for (int ks = 0; ks < 4; ks++)
        bfr[nt][ks] = *(short8*)&XT[(nt * 16 + l15) * 128 + ks * 32 + quad * 8];
    __syncthreads();                       // all frag loads done before in-place overwrite
    float4v acc[2][8];
#pragma unroll
    for (int mt = 0; mt < 2; mt++)
#pragma unroll
      for (int nt = 0; nt < 8; nt++) acc[mt][nt] = 0;
#pragma unroll
    for (int ks = 0; ks < 4; ks++)
#pragma unroll
      for (int mt = 0; mt < 2; mt++)
#pragma unroll
        for (int nt = 0; nt < 8; nt++)
          acc[mt][nt] = __builtin_amdgcn_mfma_f32_16x16x32_bf16(af[mt][ks], bfr[nt][ks], acc[mt][nt], 0, 0, 0);
    short* gX  = Spow  + (size_t)step * 16384;
    short* gXT = SpowT + (size_t)step * 16384;
#pragma unroll
    for (int mt = 0; mt < 2; mt++)
#pragma unroll
      for (int nt = 0; nt < 8; nt++) {
        int n = nt * 16 + l15;
        int mbase = wave * 32 + mt * 16 + quad * 4;
        short4v pk;
#pragma unroll
        for (int reg = 0; reg < 4; reg++) {
          short v = f2bf(acc[mt][nt][reg]);
          pk[reg] = v;
          X[(mbase + reg) * 128 + n] = v;
          gX[(mbase + reg) * 128 + n] = v;
        }
        *(short4v*)&XT[n * 128 + mbase] = pk;     // 4 consecutive m -> packed
        *(short4v*)&gXT[n * 128 + mbase] = pk;
      }
    __syncthreads();
  }
}

// ---------- wide fill: block computes one table slot via seed-product chain ----------
__global__ __launch_bounds__(256) void pow_fill(const short* __restrict__ Spow,
                                                const short* __restrict__ SpowT,
                                                short* __restrict__ P1,
                                                short* __restrict__ P1t,
                                                short* __restrict__ P2t)
{
  __shared__ short cur[16384];
  __shared__ short Bt[16384];
  int bid = blockIdx.x;
  int table1 = bid < 63;
  int e = table1 ? bid + 1 : bid - 62;
  int t = threadIdx.x;
  int lane = t & 63, wave = t >> 6, l15 = lane & 15, quad = lane >> 4;

  int bits = e;
  int k0 = __ffs(bits) - 1; bits &= bits - 1;
  int s0 = table1 ? k0 : (k0 == 0 ? 6 : 6 + k0);
  for (int i = t * 8; i < 16384; i += 2048)
    *(short8*)&cur[i] = *(const short8*)&Spow[(size_t)s0 * 16384 + i];

  while (bits) {
    int k = __ffs(bits) - 1; bits &= bits - 1;
    int si = table1 ? k : (k == 0 ? 6 : 6 + k);
    for (int i = t * 8; i < 16384; i += 2048)
      *(short8*)&Bt[i] = *(const short8*)&SpowT[(size_t)si * 16384 + i];
    __syncthreads();
    short8 af[2][4], bfr[8][4];
#pragma unroll
    for (int mt = 0; mt < 2; mt++)
#pragma unroll
      for (int ks = 0; ks < 4; ks++)
        af[mt][ks] = *(short8*)&cur[(wave * 32 + mt * 16 + l15) * 128 + ks * 32 + quad * 8];
#pragma unroll
    for (int nt = 0; nt < 8; nt++)
#pragma unroll
      for (int ks = 0; ks < 4; ks++)
        bfr[nt][ks] = *(short8*)&Bt[(nt * 16 + l15) * 128 + ks * 32 + quad * 8];
    __syncthreads();                       // loads done before in-place write of cur
    float4v acc[2][8];
#pragma unroll
    for (int mt = 0; mt < 2; mt++)
#pragma unroll
      for (int nt = 0; nt < 8; nt++) acc[mt][nt] = 0;
#pragma unroll
    for (int ks = 0; ks < 4; ks++)
#pragma unroll
      for (int mt = 0; mt < 2; mt++)
#pragma unroll
        for (int nt = 0; nt < 8; nt++)
          acc[mt][nt] = __builtin_amdgcn_mfma_f32_16x16x32_bf16(af[mt][ks], bfr[nt][ks], acc[mt][nt], 0, 0, 0);
#pragma unroll
    for (int mt = 0; mt < 2; mt++)
#pragma unroll
      for (int nt = 0; nt < 8; nt++)
#pragma unroll
        for (int reg = 0; reg < 4; reg++) {
          int m = wave * 32 + mt * 16 + quad * 4 + reg;
          int n = nt * 16 + l15;
          cur[m * 128 + n] = f2bf(acc[mt][nt][reg]);
        }
    __syncthreads();
  }
  __syncthreads();
  int slot = 63 - e;
  if (table1) {
    for (int idx = t; idx < 16384; idx += 256) {   // P1: coalesced in j
      int i = idx >> 7, j = idx & 127;
      P1[i * 8192 + slot * 128 + j] = cur[idx];
    }
    for (int idx = t; idx < 16384; idx += 256) {   // P1t: coalesced in r
      int j = idx >> 7, r = idx & 127;
      P1t[(slot * 128 + j) * 128 + r] = cur[r * 128 + j];
    }
  } else {
    for (int idx = t; idx < 16384; idx += 256) {   // P2t: coalesced in r
      int j = idx >> 7, r = idx & 127;
      P2t[(slot * 128 + j) * 128 + r] = cur[r * 128 + j];
    }
  }
}

// ---------- MFMA GEMM (V-GEMM): Vz[z][m][n] = sum_k seqs[m][k]*P1[n][k] over k-chunk z ----------
__global__ __launch_bounds__(256) void gemm_bt(
    const short* __restrict__ A_, const short* __restrict__ BT,
    float* __restrict__ out, int lda, int ldb, int ldc,
    int kSteps, int kChunk)
{
  int m0 = blockIdx.y * 128;
  int n0 = blockIdx.x * 128;
  int kBase = blockIdx.z * kChunk;

  __shared__ __align__(16) short As[128 * 64];
  __shared__ __align__(16) short Bs[128 * 64];

  int tid = threadIdx.x;
  int lane = tid & 63, wave = tid >> 6;
  int l15 = lane & 15, quad = lane >> 4;
  int wm = wave & 1, wn = wave >> 1;
  int lr = lane >> 3, lseg = lane & 7;

  float4v acc[4][4];
#pragma unroll
  for (int i = 0; i < 4; i++)
#pragma unroll
    for (int j = 0; j < 4; j++) acc[i][j] = 0;

  for (int ks = 0; ks < kSteps; ++ks) {
    int kk = kBase + ks * 64;
#pragma unroll
    for (int i = 0; i < 4; i++) {
      int rowg = wave * 32 + i * 8;
      glds16(A_ + (size_t)(m0 + rowg + lr) * lda + kk + (lseg ^ lr) * 8, &As[rowg * 64]);
      glds16(BT + (size_t)(n0 + rowg + lr) * ldb + kk + (lseg ^ lr) * 8, &Bs[rowg * 64]);
    }
    __syncthreads();
#pragma unroll
    for (int kh = 0; kh < 2; kh++) {
      int s = kh * 4 + quad;
      short8 af[4], bfr[4];
#pragma unroll
      for (int im = 0; im < 4; im++) {
        int r = wm * 64 + im * 16 + l15;
        af[im] = *(short8*)&As[r * 64 + ((s ^ (r & 7)) * 8)];
      }
#pragma unroll
      for (int in = 0; in < 4; in++) {
        int r = wn * 64 + in * 16 + l15;
        bfr[in] = *(short8*)&Bs[r * 64 + ((s ^ (r & 7)) * 8)];
      }
#pragma unroll
      for (int im = 0; im < 4; im++)
#pragma unroll
        for (int in = 0; in < 4; in++)
          acc[im][in] = __builtin_amdgcn_mfma_f32_16x16x32_bf16(af[im], bfr[in], acc[im][in], 0, 0, 0);
    }
    __syncthreads();
  }
  float* outz = out + (size_t)blockIdx.z * 65536;
#pragma unroll
  for (int im = 0; im < 4; im++)
#pragma unroll
    for (int in = 0; in < 4; in++) {
      int n = n0 + wn * 64 + in * 16 + l15;
#pragma unroll
      for (int reg = 0; reg < 4; reg++) {
        int m = m0 + wm * 64 + im * 16 + quad * 4 + reg;
        outz[(size_t)m * ldc + n] = acc[im][in][reg];
      }
    }
}

// ---------- combine: blocks = pp{0:hF via P2, 1:tail via P1} x 64 chunk-slices ----------
__global__ __launch_bounds__(256) void combine_gemm(
    const float* __restrict__ Vz, const short* __restrict__ seqs,
    const int* __restrict__ seq_lens,
    const short* __restrict__ P2t, const short* __restrict__ P1t,
    float* __restrict__ hFtail)
{
  __shared__ short X[128 * 8];   // [k_local][b] bf16
  int pp = blockIdx.x >> 6, cp = blockIdx.x & 63;
  int t = threadIdx.x;
  for (int e = t; e < 1024; e += 256) {
    int i = e >> 3, b = e & 7;
    int L = seq_lens[b];
    if (pp == 0) {
      int F = L >> 6, sh = 64 - F;
      float v = 0.f;
      if (cp >= sh) {
        int row = (b * 64 + (cp - sh)) * 128 + i;
#pragma unroll
        for (int z = 0; z < 32; z++) v += Vz[(size_t)z * 65536 + row];
      }
      X[e] = f2bf(v);
    } else {
      int F = L >> 6, rr = L & 63, sh = 64 - rr;
      short s = 0;
      if (cp >= sh) s = seqs[((size_t)b * 4096 + F * 64 + (cp - sh)) * 128 + i];
      X[e] = s;
    }
  }
  __syncthreads();
  const short* P = pp ? P1t : P2t;
  float* outp = hFtail + pp * 1024;
  int i = t & 127, g = t >> 7;
  float acc[4] = {0, 0, 0, 0};
  for (int kl = 0; kl < 128; ++kl) {
    int k = cp * 128 + kl;
    float pv = bf2f(P[k * 128 + i]);
    short4v xv = *(const short4v*)(X + kl * 8 + g * 4);
#pragma unroll
    for (int q = 0; q < 4; q++) acc[q] += bf2f(xv[q]) * pv;
  }
#pragma unroll
  for (int q = 0; q < 4; q++) atomicAdd(&outp[(g * 4 + q) * 128 + i], acc[q]);
}

// ---------- decoder stage 1: h = A^rr hF + tail, proj matvec ----------
__global__ __launch_bounds__(256) void proj_stage(
    const float* __restrict__ hFtail, const short* __restrict__ P1t,
    const int* __restrict__ seq_lens, const short* __restrict__ projB,
    const float* __restrict__ proj_b, float* __restrict__ projected)
{
  __shared__ short hT[128 * 8];        // bf16 [k][b]
  __shared__ float red[4][64][8];
  int t = threadIdx.x;
  {
    int b = t >> 5, i4 = (t & 31) * 4;
    int rr = seq_lens[b] & 63;
    const short* M = P1t + (size_t)(63 - rr) * 16384;   // (A^rr)[i][j] = M[j*128+i]
    const float* hF = hFtail + b * 128;
    float acc[4];
#pragma unroll
    for (int q = 0; q < 4; q++) acc[q] = hFtail[1024 + b * 128 + i4 + q];  // tail
    for (int j = 0; j < 128; ++j) {
      float hv = hF[j];
      short4v mv = *(const short4v*)&M[j * 128 + i4];
#pragma unroll
      for (int q = 0; q < 4; q++) acc[q] += bf2f(mv[q]) * hv;
    }
#pragma unroll
    for (int q = 0; q < 4; q++) hT[(i4 + q) * 8 + b] = f2bf(acc[q]);
  }
  __syncthreads();
  int c = t & 63, sl = t >> 6;
  int n = blockIdx.x * 64 + c;
  float acc[8] = {0, 0, 0, 0, 0, 0, 0, 0};
  for (int k = sl * 32; k < sl * 32 + 32; ++k) {
    short8 xv = *(short8*)&hT[k * 8];
    float wv = bf2f(projB[k * 1024 + n]);
#pragma unroll
    for (int b = 0; b < 8; b++) acc[b] += bf2f(xv[b]) * wv;
  }
#pragma unroll
  for (int b = 0; b < 8; b++) red[sl][c][b] = acc[b];
  __syncthreads();
  if (sl == 0) {
#pragma unroll
    for (int s = 1; s < 4; s++)
#pragma unroll
      for (int b = 0; b < 8; b++) acc[b] += red[s][c][b];
    float bn = proj_b[n];
#pragma unroll
    for (int b = 0; b < 8; b++) projected[b * 1024 + n] = acc[b] + bn;
  }
}

// ---------- decoder stage 2: LN1(projected) @ ffn_w1 -> ffn1raw (128-block split-K) ----------
__global__ __launch_bounds__(256) void ffn1_stage(
    const float* __restrict__ projected, const float* __restrict__ g1,
    const float* __restrict__ b1, const short* __restrict__ ffn1B,
    float* __restrict__ ffn1raw)
{
  __shared__ float part[8][32][2];
  __shared__ float stats[8][2];
  __shared__ short xT[64 * 8];
  __shared__ float red[4][64][8];
  int t = threadIdx.x;
  { int b = t >> 5, j0 = t & 31; float s = 0, q = 0;
    for (int k = j0 * 32; k < j0 * 32 + 32; ++k) { float v = projected[b * 1024 + k]; s += v; q += v * v; }
    part[b][j0][0] = s; part[b][j0][1] = q; }
  __syncthreads();
  if (t < 8) {
    float s = 0, q = 0;
    for (int j = 0; j < 32; j++) { s += part[t][j][0]; q += part[t][j][1]; }
    float mu = s * (1.0f / 1024.0f);
    float var = q * (1.0f / 1024.0f) - mu * mu;
    stats[t][0] = mu; stats[t][1] = rsqrtf(var + 1e-5f);
  }
  __syncthreads();
  int ky0 = blockIdx.y * 64;
  for (int idx = t; idx < 512; idx += 256) {
    int kl = idx >> 3, b = idx & 7; int k = ky0 + kl;
    float v = (projected[b * 1024 + k] - stats[b][0]) * stats[b][1] * g1[k] + b1[k];
    xT[kl * 8 + b] = f2bf(v);
  }
  __syncthreads();
  int c = t & 63, sl = t >> 6;
  int n = blockIdx.x * 64 + c;
  float acc[8] = {0, 0, 0, 0, 0, 0, 0, 0};
  for (int kl = sl * 16; kl < sl * 16 + 16; ++kl) {
    short8 xv = *(short8*)&xT[kl * 8];
    float wv = bf2f(ffn1B[(size_t)(ky0 + kl) * 512 + n]);
#pragma unroll
    for (int b = 0; b < 8; b++) acc[b] += bf2f(xv[b]) * wv;
  }
#pragma unroll
  for (int b = 0; b < 8; b++) red[sl][c][b] = acc[b];
  __syncthreads();
  if (sl == 0) {
#pragma unroll
    for (int s = 1; s < 4; s++)
#pragma unroll
      for (int b = 0; b < 8; b++) acc[b] += red[s][c][b];
#pragma unroll
    for (int b = 0; b < 8; b++) atomicAdd(&ffn1raw[b * 512 + n], acc[b]);
  }
}

// ---------- decoder stage 3: gelu(ffn1raw + b1) @ ffn_w2 -> ffn2raw (128-block split-K) ----------
__global__ __launch_bounds__(256) void ffn2_stage(
    const float* __restrict__ ffn1raw, const float* __restrict__ fb1,
    const short* __restrict__ ffn2B, float* __restrict__ ffn2raw)
{
  __shared__ short xT[64 * 8];
  __shared__ float red[4][64][8];
  int t = threadIdx.x;
  int ky0 = blockIdx.y * 64;
  for (int idx = t; idx < 512; idx += 256) {
    int kl = idx >> 3, b = idx & 7; int k = ky0 + kl;
    float v = gelu_f(ffn1raw[b * 512 + k] + fb1[k]);
    xT[kl * 8 + b] = f2bf(v);
  }
  __syncthreads();
  int c = t & 63, sl = t >> 6;
  int n = blockIdx.x * 64 + c;
  float acc[8] = {0, 0, 0, 0, 0, 0, 0, 0};
  for (int kl = sl * 16; kl < sl * 16 + 16; ++kl) {
    short8 xv = *(short8*)&xT[kl * 8];
    float wv = bf2f(ffn2B[(size_t)(ky0 + kl) * 1024 + n]);
#pragma unroll
    for (int b = 0; b < 8; b++) acc[b] += bf2f(xv[b]) * wv;
  }
#pragma unroll
  for (int b = 0; b < 8; b++) red[sl][c][b] = acc[b];
  __syncthreads();
  if (sl == 0) {
#pragma unroll
    for (int s = 1; s < 4; s++)
#pragma unroll
      for (int b = 0; b < 8; b++) acc[b] += red[s][c][b];
#pragma unroll
    for (int b = 0; b < 8; b++) atomicAdd(&ffn2raw[b * 1024 + n], acc[b]);
  }
}

// ---------- decoder stage 4: LN2(ffn2raw+b2+projected) @ out_w + out_b -> d_out (128-block) ----------
__global__ __launch_bounds__(256) void out_stage(
    const float* __restrict__ ffn2raw, const float* __restrict__ fb2,
    const float* __restrict__ projected, const float* __restrict__ g2,
    const float* __restrict__ b2ln, const short* __restrict__ outB,
    const float* __restrict__ out_b, float* __restrict__ d_out)
{
  __shared__ float part[8][32][2];
  __shared__ float stats[8][2];
  __shared__ short xT[128 * 8];
  __shared__ float red[4][64][8];
  int t = threadIdx.x;
  { int b = t >> 5, j0 = t & 31; float s = 0, q = 0;
    for (int k = j0 * 32; k < j0 * 32 + 32; ++k) {
      float v = ffn2raw[b * 1024 + k] + fb2[k] + projected[b * 1024 + k];
      s += v; q += v * v;
    }
    part[b][j0][0] = s; part[b][j0][1] = q; }
  __syncthreads();
  if (t < 8) {
    float s = 0, q = 0;
    for (int j = 0; j < 32; j++) { s += part[t][j][0]; q += part[t][j][1]; }
    float mu = s * (1.0f / 1024.0f);
    float var = q * (1.0f / 1024.0f) - mu * mu;
    stats[t][0] = mu; stats[t][1] = rsqrtf(var + 1e-5f);
  }
  __syncthreads();
  int ky0 = blockIdx.y * 128;
  for (int idx = t; idx < 1024; idx += 256) {
    int kl = idx >> 3, b = idx & 7; int k = ky0 + kl;
    float v = ffn2raw[b * 1024 + k] + fb2[k] + projected[b * 1024 + k];
    v = (v - stats[b][0]) * stats[b][1] * g2[k] + b2ln[k];
    xT[kl * 8 + b] = f2bf(v);
  }
  __syncthreads();
  int c = t & 63, sl = t >> 6;
  int n = blockIdx.x * 64 + c;
  float acc[8] = {0, 0, 0, 0, 0, 0, 0, 0};
  for (int kl = sl * 32; kl < sl * 32 + 32; ++kl) {
    short8 xv = *(short8*)&xT[kl * 8];
    float wv = bf2f(outB[(size_t)(ky0 + kl) * 1024 + n]);
#pragma unroll
    for (int b = 0; b < 8; b++) acc[b] += bf2f(xv[b]) * wv;
  }
#pragma unroll
  for (int b = 0; b < 8; b++) red[sl][c][b] = acc[b];
  __syncthreads();
  if (sl == 0) {
#pragma unroll
    for (int s = 1; s < 4; s++)
#pragma unroll
      for (int b = 0; b < 8; b++) acc[b] += red[s][c][b];
    float bn = (blockIdx.y == 0) ? out_b[n] : 0.0f;
#pragma unroll
    for (int b = 0; b < 8; b++) atomicAdd(&d_out[b * 1024 + n], acc[b] + bn);
  }
}

// ---------- host ----------
extern "C" void kernel_launch(void* const* d_in, const int* in_sizes, int n_in,
                              void* d_out, int out_size, void* d_ws, size_t ws_size,
                              hipStream_t stream)
{
  (void)in_sizes; (void)n_in; (void)out_size; (void)ws_size;
  const float* x      = (const float*)d_in[0];
  const int* seq_lens = (const int*)d_in[1];
  const float* A      = (const float*)d_in[2];
  const float* enc_w1 = (const float*)d_in[3];
  const float* enc_b1 = (const float*)d_in[4];
  const float* enc_w2 = (const float*)d_in[5];
  const float* enc_b2 = (const float*)d_in[6];
  const float* proj_w = (const float*)d_in[7];
  const float* proj_b = (const float*)d_in[8];
  const float* ln1_g  = (const float*)d_in[9];
  const float* ln1_b  = (const float*)d_in[10];
  const float* ffn_w1 = (const float*)d_in[11];
  const float* ffn_b1 = (const float*)d_in[12];
  const float* ffn_w2 = (const float*)d_in[13];
  const float* ffn_b2 = (const float*)d_in[14];
  const float* ln2_g  = (const float*)d_in[15];
  const float* ln2_b  = (const float*)d_in[16];
  const float* out_w  = (const float*)d_in[17];
  const float* out_b  = (const float*)d_in[18];

  char* p = (char*)d_ws;
  auto alloc = [&](size_t bytes) { char* r = p; p += (bytes + 255) & ~(size_t)255; return r; };
  short* xB    = (short*)alloc(32768ull * 384 * 2);     // 25 MB
  float* encP  = (float*)alloc(4ull * 32768 * 128 * 4); // 64 MB partials
  short* seqs  = (short*)alloc(32768ull * 128 * 2);     // 8.4 MB
  short* w1T   = (short*)alloc(1024ull * 384 * 2);
  short* w2T   = (short*)alloc(128ull * 1024 * 2);
  short* projB = (short*)alloc(128ull * 1024 * 2);
  short* ffn1B = (short*)alloc(1024ull * 512 * 2);
  short* ffn2B = (short*)alloc(512ull * 1024 * 2);
  short* outB  = (short*)alloc(1024ull * 1024 * 2);
  short* Spow  = (short*)alloc(12ull * 16384 * 2);
  short* SpowT = (short*)alloc(12ull * 16384 * 2);
  short* P1    = (short*)alloc(128ull * 8192 * 2);      // [i][(63-e)*128+j] = A^e
  short* P1t   = (short*)alloc(8192ull * 128 * 2);
  short* P2t   = (short*)alloc(8192ull * 128 * 2);
  float* Vz    = (float*)alloc(32ull * 512 * 128 * 4);  // per-z V partials
  float* hFtail  = (float*)alloc(2048ull * 4);          // zeroed by prep
  float* ffn1raw = (float*)alloc(8ull * 512 * 4);       // zeroed by prep
  float* ffn2raw = (float*)alloc(8ull * 1024 * 4);      // zeroed by prep
  float* projected = (float*)alloc(8ull * 1024 * 4);
  int*   encCnt  = (int*)alloc(512ull * 4);             // zeroed by prep

  // node 1: conversions + seeds + zero-init (no memsets anywhere)
  prep_wide<<<23194, 256, 0, stream>>>(x, enc_w1, enc_w2, proj_w, ffn_w1, ffn_w2, out_w,
      A, seq_lens, xB, w1T, w2T, projB, ffn1B, ffn2B, outB, P1, P1t, P2t,
      Spow, SpowT, hFtail, ffn1raw, ffn2raw, (float*)d_out, encCnt);

  // power tables
  pow_chain<<<1, 256, 0, stream>>>(Spow, SpowT);
  pow_fill<<<126, 256, 0, stream>>>(Spow, SpowT, P1, P1t, P2t);

  // fused encoder (GEMM1+GELU+GEMM2, 4-way split) + in-kernel reduction -> seqs
  enc_fused<<<dim3(512, 4), 256, 0, stream>>>(xB, w1T, w2T, enc_b1, enc_b2,
      encP, seqs, encCnt, seq_lens);

  // recurrence: per-chunk values (32-way z partials), then shifted combine + tail
  gemm_bt<<<dim3(1, 4, 32), 256, 0, stream>>>(seqs, P1, Vz, 8192, 8192, 128, 4, 256);
  combine_gemm<<<128, 256, 0, stream>>>(Vz, seqs, seq_lens, P2t, P1t, hFtail);

  // decoder (wide split-K, atomics into prep-zeroed accumulators)
  proj_stage<<<16, 256, 0, stream>>>(hFtail, P1t, seq_lens, projB, proj_b, projected);
  ffn1_stage<<<dim3(8, 16), 256, 0, stream>>>(projected, ln1_g, ln1_b, ffn1B, ffn1raw);
  ffn2_stage<<<dim3(16, 8), 256, 0, stream>>>(ffn1raw, ffn_b1, ffn2B, ffn2raw);
  out_stage<<<dim3(16, 8), 256, 0, stream>>>(ffn2raw, ffn_b2, projected, ln2_g, ln2_b,
      outB, out_b, (float*)d_out);
}